// Round 3
// baseline (1785.731 us; speedup 1.0000x reference)
//
#include <hip/hip_runtime.h>
#include <stdint.h>

#define NSITES 256
#define NHID   64
#define BATCH  8192

// ---------------- threefry2x32 (exact JAX semantics) ----------------
__device__ __forceinline__ uint32_t rotl32(uint32_t v, int d) {
  return (v << d) | (v >> (32 - d));
}

__device__ __forceinline__ void tf2x32(uint32_t k0, uint32_t k1,
                                       uint32_t x0, uint32_t x1,
                                       uint32_t& o0, uint32_t& o1) {
  uint32_t ks2 = k0 ^ k1 ^ 0x1BD11BDAu;
  x0 += k0; x1 += k1;
#define TFR4(a,b,c,d) \
  x0 += x1; x1 = rotl32(x1,a); x1 ^= x0; \
  x0 += x1; x1 = rotl32(x1,b); x1 ^= x0; \
  x0 += x1; x1 = rotl32(x1,c); x1 ^= x0; \
  x0 += x1; x1 = rotl32(x1,d); x1 ^= x0;
  TFR4(13,15,26,6)   x0 += k1;  x1 += ks2 + 1u;
  TFR4(17,29,16,24)  x0 += ks2; x1 += k0  + 2u;
  TFR4(13,15,26,6)   x0 += k0;  x1 += k1  + 3u;
  TFR4(17,29,16,24)  x0 += k1;  x1 += ks2 + 4u;
  TFR4(13,15,26,6)   x0 += ks2; x1 += k0  + 5u;
#undef TFR4
  o0 = x0; o1 = x1;
}

__device__ __forceinline__ float gumb_from_bits(uint32_t bits) {
  float f = __uint_as_float((bits >> 9) | 0x3f800000u) - 1.0f;
  float u = (f == 0.0f) ? 1.17549435e-38f : f;
  return -logf(-logf(u));
}

__device__ __forceinline__ uint32_t rbits32(uint32_t k0, uint32_t k1, uint32_t e) {
  uint32_t a, b;
  tf2x32(k0, k1, 0u, e, a, b);
  return a ^ b;
}

// ---------------- gumbel precompute kernel ----------------
__global__ void gumbel_precompute(float2* __restrict__ g) {
  int idx = blockIdx.x * blockDim.x + threadIdx.x;
  if (idx >= NSITES * BATCH) return;
  int t = idx >> 13;
  int b = idx & (BATCH - 1);
  uint32_t kt0, kt1;
  tf2x32(0u, 1234u, 0u, (uint32_t)t, kt0, kt1);
  uint32_t r0 = rbits32(kt0, kt1, (uint32_t)(2 * b));
  uint32_t r1 = rbits32(kt0, kt1, (uint32_t)(2 * b + 1));
  g[idx] = make_float2(gumb_from_bits(r0), gumb_from_bits(r1));
}

// XLA's logistic_expander form: 0.5 + 0.5*tanh(0.5*x)
__device__ __forceinline__ float sigmoid_xla(float x) {
  return 0.5f + 0.5f * tanhf(0.5f * x);
}

// ================= v1: one sample per wave, weights VGPR-resident =========
// amdgpu_waves_per_eu(2,2) pins the allocator budget at 256 VGPR so the 192
// weight values stay resident (round-2's launch_bounds min-arg let the
// heuristic target 4 waves/EU -> VGPR<=128 -> loads rematerialized in-loop).
template <bool PRE>
__global__ __launch_bounds__(64) __attribute__((amdgpu_waves_per_eu(2, 2)))
void rnn_v1(const float* __restrict__ Wi, const float* __restrict__ Wh,
            const float* __restrict__ bb, const float* __restrict__ Wd,
            const float* __restrict__ bd, const float2* __restrict__ g,
            float* __restrict__ out_s, float* __restrict__ out_lp, int base) {
  const int lane = threadIdx.x;
  const int b = base + blockIdx.x;

  float wz[NHID], wr[NHID], wh[NHID];
#pragma unroll
  for (int j = 0; j < NHID; ++j) {
    wz[j] = Wh[j * 192 + lane];
    wr[j] = Wh[j * 192 + 64 + lane];
    wh[j] = Wh[j * 192 + 128 + lane];
  }
#pragma unroll
  for (int j = 0; j < NHID; ++j)
    asm("" : "+v"(wz[j]), "+v"(wr[j]), "+v"(wh[j]));

  const float b1z = bb[192 + lane];
  const float b1r = bb[192 + 64 + lane];
  const float b1h = bb[192 + 128 + lane];
  const float m0z = bb[lane], m0r = bb[64 + lane], m0h = bb[128 + lane];
  const float m1z = Wi[lane] + m0z, m1r = Wi[64 + lane] + m0r, m1h = Wi[128 + lane] + m0h;
  const float m2z = Wi[192 + lane] + m0z, m2r = Wi[192 + 64 + lane] + m0r,
              m2h = Wi[192 + 128 + lane] + m0h;
  const float wd0 = Wd[lane * 2 + 0], wd1 = Wd[lane * 2 + 1];
  const float bd0 = bd[0], bd1 = bd[1];

  float h = 0.0f, lpsum = 0.0f;
  float xz = m0z, xr = m0r, xh = m0h;   // t=0: zero one-hot input

  for (int t = 0; t < NSITES; ++t) {
    float g0, g1;
    if (PRE) {
      const float2 gc = g[t * BATCH + b];
      g0 = gc.x; g1 = gc.y;
    } else {
      uint32_t kt0, kt1;
      tf2x32(0u, 1234u, 0u, (uint32_t)t, kt0, kt1);
      g0 = gumb_from_bits(rbits32(kt0, kt1, (uint32_t)(2 * b)));
      g1 = gumb_from_bits(rbits32(kt0, kt1, (uint32_t)(2 * b + 1)));
    }

    float az = 0.0f, ar = 0.0f, ah = 0.0f;
#pragma unroll
    for (int j = 0; j < NHID; ++j) {
      const float hj = __int_as_float(__builtin_amdgcn_readlane(__float_as_int(h), j));
      az = fmaf(hj, wz[j], az);
      ar = fmaf(hj, wr[j], ar);
      ah = fmaf(hj, wh[j], ah);
    }
    const float rz = az + b1z;
    const float rr = ar + b1r;
    const float rh = ah + b1h;

    const float zg = sigmoid_xla(xz + rz);
    const float rg = sigmoid_xla(xr + rr);
    const float hg = tanhf(xh + rg * rh);
    h = zg * h + (1.0f - zg) * hg;

    float p0 = h * wd0, p1 = h * wd1;
#pragma unroll
    for (int off = 32; off > 0; off >>= 1) {
      p0 += __shfl_xor(p0, off, 64);
      p1 += __shfl_xor(p1, off, 64);
    }
    const float l0 = p0 + bd0, l1 = p1 + bd1;

    const float mmax = fmaxf(l0, l1);
    const float sh0 = l0 - mmax, sh1 = l1 - mmax;
    const float lse = logf(expf(sh0) + expf(sh1));

    const int s = ((l1 + g1) > (l0 + g0)) ? 1 : 0;

    lpsum += (s ? sh1 : sh0) - lse;
    if (lane == 0) out_s[(size_t)b * NSITES + t] = (float)s;
    xz = s ? m2z : m1z;
    xr = s ? m2r : m1r;
    xh = s ? m2h : m1h;
  }

  if (lane == 0) out_lp[b] = 0.5f * lpsum;
}

// ================= v2: TWO samples per wave (shared weight registers) =====
// Same bit-exact math per sample; two independent dependency chains per wave
// to fill latency bubbles (butterfly DS waits, tanh chains) at 2 waves/SIMD.
__global__ __launch_bounds__(64) __attribute__((amdgpu_waves_per_eu(2, 2)))
void rnn_v2(const float* __restrict__ Wi, const float* __restrict__ Wh,
            const float* __restrict__ bb, const float* __restrict__ Wd,
            const float* __restrict__ bd, const float2* __restrict__ g,
            float* __restrict__ out_s, float* __restrict__ out_lp, int base) {
  const int lane = threadIdx.x;
  const int bA = base + blockIdx.x * 2;   // even
  // bB = bA + 1

  float wz[NHID], wr[NHID], wh[NHID];
#pragma unroll
  for (int j = 0; j < NHID; ++j) {
    wz[j] = Wh[j * 192 + lane];
    wr[j] = Wh[j * 192 + 64 + lane];
    wh[j] = Wh[j * 192 + 128 + lane];
  }
#pragma unroll
  for (int j = 0; j < NHID; ++j)
    asm("" : "+v"(wz[j]), "+v"(wr[j]), "+v"(wh[j]));

  const float b1z = bb[192 + lane];
  const float b1r = bb[192 + 64 + lane];
  const float b1h = bb[192 + 128 + lane];
  const float m0z = bb[lane], m0r = bb[64 + lane], m0h = bb[128 + lane];
  const float m1z = Wi[lane] + m0z, m1r = Wi[64 + lane] + m0r, m1h = Wi[128 + lane] + m0h;
  const float m2z = Wi[192 + lane] + m0z, m2r = Wi[192 + 64 + lane] + m0r,
              m2h = Wi[192 + 128 + lane] + m0h;
  const float wd0 = Wd[lane * 2 + 0], wd1 = Wd[lane * 2 + 1];
  const float bd0 = bd[0], bd1 = bd[1];

  float hA = 0.0f, lpA = 0.0f, hB = 0.0f, lpB = 0.0f;
  float xzA = m0z, xrA = m0r, xhA = m0h;
  float xzB = m0z, xrB = m0r, xhB = m0h;

  for (int t = 0; t < NSITES; ++t) {
    // adjacent float2s -> one 16B load (bA even => 16B-aligned)
    const float4 g4 = *reinterpret_cast<const float4*>(&g[t * BATCH + bA]);

    float azA = 0.0f, arA = 0.0f, ahA = 0.0f;
    float azB = 0.0f, arB = 0.0f, ahB = 0.0f;
#pragma unroll
    for (int j = 0; j < NHID; ++j) {
      const float hjA = __int_as_float(__builtin_amdgcn_readlane(__float_as_int(hA), j));
      const float hjB = __int_as_float(__builtin_amdgcn_readlane(__float_as_int(hB), j));
      azA = fmaf(hjA, wz[j], azA);
      azB = fmaf(hjB, wz[j], azB);
      arA = fmaf(hjA, wr[j], arA);
      arB = fmaf(hjB, wr[j], arB);
      ahA = fmaf(hjA, wh[j], ahA);
      ahB = fmaf(hjB, wh[j], ahB);
    }
    const float rzA = azA + b1z, rrA = arA + b1r, rhA = ahA + b1h;
    const float rzB = azB + b1z, rrB = arB + b1r, rhB = ahB + b1h;

    const float zgA = sigmoid_xla(xzA + rzA);
    const float zgB = sigmoid_xla(xzB + rzB);
    const float rgA = sigmoid_xla(xrA + rrA);
    const float rgB = sigmoid_xla(xrB + rrB);
    const float hgA = tanhf(xhA + rgA * rhA);
    const float hgB = tanhf(xhB + rgB * rhB);
    hA = zgA * hA + (1.0f - zgA) * hgA;
    hB = zgB * hB + (1.0f - zgB) * hgB;

    float p0A = hA * wd0, p1A = hA * wd1;
    float p0B = hB * wd0, p1B = hB * wd1;
#pragma unroll
    for (int off = 32; off > 0; off >>= 1) {
      p0A += __shfl_xor(p0A, off, 64);
      p1A += __shfl_xor(p1A, off, 64);
      p0B += __shfl_xor(p0B, off, 64);
      p1B += __shfl_xor(p1B, off, 64);
    }
    const float l0A = p0A + bd0, l1A = p1A + bd1;
    const float l0B = p0B + bd0, l1B = p1B + bd1;

    const float mmA = fmaxf(l0A, l1A);
    const float sh0A = l0A - mmA, sh1A = l1A - mmA;
    const float lseA = logf(expf(sh0A) + expf(sh1A));
    const float mmB = fmaxf(l0B, l1B);
    const float sh0B = l0B - mmB, sh1B = l1B - mmB;
    const float lseB = logf(expf(sh0B) + expf(sh1B));

    const int sA = ((l1A + g4.y) > (l0A + g4.x)) ? 1 : 0;
    const int sB = ((l1B + g4.w) > (l0B + g4.z)) ? 1 : 0;

    lpA += (sA ? sh1A : sh0A) - lseA;
    lpB += (sB ? sh1B : sh0B) - lseB;

    if (lane < 2) {
      const float sv = lane ? (float)sB : (float)sA;
      out_s[(size_t)(bA + lane) * NSITES + t] = sv;
    }
    xzA = sA ? m2z : m1z; xrA = sA ? m2r : m1r; xhA = sA ? m2h : m1h;
    xzB = sB ? m2z : m1z; xrB = sB ? m2r : m1r; xhB = sB ? m2h : m1h;
  }

  if (lane < 2) out_lp[bA + lane] = 0.5f * (lane ? lpB : lpA);
}

extern "C" void kernel_launch(void* const* d_in, const int* in_sizes, int n_in,
                              void* d_out, int out_size, void* d_ws, size_t ws_size,
                              hipStream_t stream) {
  const float* Wi = (const float*)d_in[1];
  const float* Wh = (const float*)d_in[2];
  const float* bb = (const float*)d_in[3];
  const float* Wd = (const float*)d_in[4];
  const float* bd = (const float*)d_in[5];

  float* out    = (float*)d_out;
  float* out_s  = out;                           // [8192][256]
  float* out_lp = out + (size_t)BATCH * NSITES;  // [8192]

  const size_t gbytes = (size_t)NSITES * BATCH * sizeof(float2);
  if (ws_size >= gbytes) {
    float2* g = (float2*)d_ws;
    gumbel_precompute<<<(NSITES * BATCH) / 256, 256, 0, stream>>>(g);
    // within-probe A/B: v1 on samples [0,4096), v2 on [4096,8192)
    rnn_v1<true><<<BATCH / 2, 64, 0, stream>>>(Wi, Wh, bb, Wd, bd, g, out_s, out_lp, 0);
    rnn_v2<<<BATCH / 4, 64, 0, stream>>>(Wi, Wh, bb, Wd, bd, g, out_s, out_lp, BATCH / 2);
  } else {
    rnn_v1<false><<<BATCH, 64, 0, stream>>>(Wi, Wh, bb, Wd, bd, nullptr, out_s, out_lp, 0);
  }
}

// Round 4
// 1439.040 us; speedup vs baseline: 1.2409x; 1.2409x over previous
//
#include <hip/hip_runtime.h>
#include <stdint.h>

#define NSITES 256
#define NHID   64
#define BATCH  8192

// ---------------- threefry2x32 (exact JAX semantics) ----------------
__device__ __forceinline__ uint32_t rotl32(uint32_t v, int d) {
  return (v << d) | (v >> (32 - d));
}

__device__ __forceinline__ void tf2x32(uint32_t k0, uint32_t k1,
                                       uint32_t x0, uint32_t x1,
                                       uint32_t& o0, uint32_t& o1) {
  uint32_t ks2 = k0 ^ k1 ^ 0x1BD11BDAu;
  x0 += k0; x1 += k1;
#define TFR4(a,b,c,d) \
  x0 += x1; x1 = rotl32(x1,a); x1 ^= x0; \
  x0 += x1; x1 = rotl32(x1,b); x1 ^= x0; \
  x0 += x1; x1 = rotl32(x1,c); x1 ^= x0; \
  x0 += x1; x1 = rotl32(x1,d); x1 ^= x0;
  TFR4(13,15,26,6)   x0 += k1;  x1 += ks2 + 1u;
  TFR4(17,29,16,24)  x0 += ks2; x1 += k0  + 2u;
  TFR4(13,15,26,6)   x0 += k0;  x1 += k1  + 3u;
  TFR4(17,29,16,24)  x0 += k1;  x1 += ks2 + 4u;
  TFR4(13,15,26,6)   x0 += ks2; x1 += k0  + 5u;
#undef TFR4
  o0 = x0; o1 = x1;
}

__device__ __forceinline__ float gumb_from_bits(uint32_t bits) {
  float f = __uint_as_float((bits >> 9) | 0x3f800000u) - 1.0f;
  float u = (f == 0.0f) ? 1.17549435e-38f : f;
  return -logf(-logf(u));
}

__device__ __forceinline__ uint32_t rbits32(uint32_t k0, uint32_t k1, uint32_t e) {
  uint32_t a, b;
  tf2x32(k0, k1, 0u, e, a, b);
  return a ^ b;
}

// ---------------- gumbel precompute kernel ----------------
__global__ void gumbel_precompute(float2* __restrict__ g) {
  int idx = blockIdx.x * blockDim.x + threadIdx.x;
  if (idx >= NSITES * BATCH) return;
  int t = idx >> 13;
  int b = idx & (BATCH - 1);
  uint32_t kt0, kt1;
  tf2x32(0u, 1234u, 0u, (uint32_t)t, kt0, kt1);
  uint32_t r0 = rbits32(kt0, kt1, (uint32_t)(2 * b));
  uint32_t r1 = rbits32(kt0, kt1, (uint32_t)(2 * b + 1));
  g[idx] = make_float2(gumb_from_bits(r0), gumb_from_bits(r1));
}

// XLA's logistic_expander form: 0.5 + 0.5*tanh(0.5*x)
__device__ __forceinline__ float sigmoid_xla(float x) {
  return 0.5f + 0.5f * tanhf(0.5f * x);
}

// ================= one sample per wave, weights VGPR-resident =============
// The 192 per-lane Wh values are pinned with `asm volatile` ("+v") after the
// load: a volatile asm's execution count may not be changed by the compiler,
// so the values cannot be rematerialized/re-loaded inside the t-loop (which
// is what kept rounds 1-3 at ~2x the ideal per-step instruction count).
// amdgpu_waves_per_eu(2,2) gives the allocator a 256-VGPR budget so the
// ~225-register live set fits without scratch spills.
template <bool PRE>
__global__ __launch_bounds__(64) __attribute__((amdgpu_waves_per_eu(2, 2)))
void rnn_v1(const float* __restrict__ Wi, const float* __restrict__ Wh,
            const float* __restrict__ bb, const float* __restrict__ Wd,
            const float* __restrict__ bd, const float2* __restrict__ g,
            float* __restrict__ out_s, float* __restrict__ out_lp) {
  const int lane = threadIdx.x;
  const int b = blockIdx.x;

  float wz[NHID], wr[NHID], wh[NHID];
#pragma unroll
  for (int j = 0; j < NHID; ++j) {
    wz[j] = Wh[j * 192 + lane];
    wr[j] = Wh[j * 192 + 64 + lane];
    wh[j] = Wh[j * 192 + 128 + lane];
    // volatile: cannot be duplicated/rematerialized -> values must stay live
    asm volatile("" : "+v"(wz[j]), "+v"(wr[j]), "+v"(wh[j]));
  }

  const float b1z = bb[192 + lane];
  const float b1r = bb[192 + 64 + lane];
  const float b1h = bb[192 + 128 + lane];
  const float m0z = bb[lane], m0r = bb[64 + lane], m0h = bb[128 + lane];
  const float m1z = Wi[lane] + m0z, m1r = Wi[64 + lane] + m0r, m1h = Wi[128 + lane] + m0h;
  const float m2z = Wi[192 + lane] + m0z, m2r = Wi[192 + 64 + lane] + m0r,
              m2h = Wi[192 + 128 + lane] + m0h;
  const float wd0 = Wd[lane * 2 + 0], wd1 = Wd[lane * 2 + 1];
  const float bd0 = bd[0], bd1 = bd[1];

  float h = 0.0f, lpsum = 0.0f;
  float xz = m0z, xr = m0r, xh = m0h;   // t=0: zero one-hot input

  for (int t = 0; t < NSITES; ++t) {
    float g0, g1;
    if (PRE) {
      const float2 gc = g[t * BATCH + b];
      g0 = gc.x; g1 = gc.y;
    } else {
      uint32_t kt0, kt1;
      tf2x32(0u, 1234u, 0u, (uint32_t)t, kt0, kt1);
      g0 = gumb_from_bits(rbits32(kt0, kt1, (uint32_t)(2 * b)));
      g1 = gumb_from_bits(rbits32(kt0, kt1, (uint32_t)(2 * b + 1)));
    }

    float az = 0.0f, ar = 0.0f, ah = 0.0f;
#pragma unroll
    for (int j = 0; j < NHID; ++j) {
      const float hj = __int_as_float(__builtin_amdgcn_readlane(__float_as_int(h), j));
      az = fmaf(hj, wz[j], az);
      ar = fmaf(hj, wr[j], ar);
      ah = fmaf(hj, wh[j], ah);
    }
    const float rz = az + b1z;
    const float rr = ar + b1r;
    const float rh = ah + b1h;

    const float zg = sigmoid_xla(xz + rz);
    const float rg = sigmoid_xla(xr + rr);
    const float hg = tanhf(xh + rg * rh);
    h = zg * h + (1.0f - zg) * hg;

    float p0 = h * wd0, p1 = h * wd1;
#pragma unroll
    for (int off = 32; off > 0; off >>= 1) {
      p0 += __shfl_xor(p0, off, 64);
      p1 += __shfl_xor(p1, off, 64);
    }
    const float l0 = p0 + bd0, l1 = p1 + bd1;

    const float mmax = fmaxf(l0, l1);
    const float sh0 = l0 - mmax, sh1 = l1 - mmax;
    const float lse = logf(expf(sh0) + expf(sh1));

    const int s = ((l1 + g1) > (l0 + g0)) ? 1 : 0;

    lpsum += (s ? sh1 : sh0) - lse;
    if (lane == 0) out_s[(size_t)b * NSITES + t] = (float)s;
    xz = s ? m2z : m1z;
    xr = s ? m2r : m1r;
    xh = s ? m2h : m1h;
  }

  if (lane == 0) out_lp[b] = 0.5f * lpsum;
}

extern "C" void kernel_launch(void* const* d_in, const int* in_sizes, int n_in,
                              void* d_out, int out_size, void* d_ws, size_t ws_size,
                              hipStream_t stream) {
  const float* Wi = (const float*)d_in[1];
  const float* Wh = (const float*)d_in[2];
  const float* bb = (const float*)d_in[3];
  const float* Wd = (const float*)d_in[4];
  const float* bd = (const float*)d_in[5];

  float* out    = (float*)d_out;
  float* out_s  = out;                           // [8192][256]
  float* out_lp = out + (size_t)BATCH * NSITES;  // [8192]

  const size_t gbytes = (size_t)NSITES * BATCH * sizeof(float2);
  if (ws_size >= gbytes) {
    float2* g = (float2*)d_ws;
    gumbel_precompute<<<(NSITES * BATCH) / 256, 256, 0, stream>>>(g);
    rnn_v1<true><<<BATCH, 64, 0, stream>>>(Wi, Wh, bb, Wd, bd, g, out_s, out_lp);
  } else {
    rnn_v1<false><<<BATCH, 64, 0, stream>>>(Wi, Wh, bb, Wd, bd, nullptr, out_s, out_lp);
  }
}